// Round 2
// baseline (711.430 us; speedup 1.0000x reference)
//
#include <hip/hip_runtime.h>
#include <hip/hip_bf16.h>
#include <stdint.h>

#define TOK   16384
#define DDIM  1024
#define NEXP  8
#define KTOT  (NEXP * DDIM)   // 8192

#define BM 128
#define BN 128
#define BK 32
#define ALD 40                // As leading dim (32 + 8 pad): bank-perfect for b128

typedef __attribute__((ext_vector_type(8))) short  short8;
typedef __attribute__((ext_vector_type(4))) float  floatx4;

// round-to-nearest-even f32 -> bf16 (data is normal-range; NaN path not needed)
static __device__ __forceinline__ unsigned int bf16_rne(float f) {
  unsigned int u = __builtin_bit_cast(unsigned int, f);
  return (u + 0x7fffu + ((u >> 16) & 1u)) >> 16;
}
static __device__ __forceinline__ unsigned int pack_bf16x2(float a, float b) {
  return bf16_rne(a) | (bf16_rne(b) << 16);
}

// ---------------------------------------------------------------------------
// Kernel 1: fp32 gate. One wave per token. probs = softmax(x @ gate_w + gate_b),
// select >= 0.1, renormalize. Writes w[TOK][8] fp32.
// ---------------------------------------------------------------------------
__global__ __launch_bounds__(256) void gate_kernel(
    const float* __restrict__ x, const float* __restrict__ gw,
    const float* __restrict__ gb, float* __restrict__ wout) {
  int wave = threadIdx.x >> 6;
  int lane = threadIdx.x & 63;
  int t = blockIdx.x * 4 + wave;
  const float* xr = x + (size_t)t * DDIM;

  float acc[8];
#pragma unroll
  for (int e = 0; e < 8; ++e) acc[e] = 0.f;

#pragma unroll
  for (int i = 0; i < DDIM / 64; ++i) {
    int k = lane + 64 * i;
    float xv = xr[k];
    const float4* g = (const float4*)(gw + (size_t)k * 8);
    float4 g0 = g[0];
    float4 g1 = g[1];
    acc[0] += xv * g0.x; acc[1] += xv * g0.y;
    acc[2] += xv * g0.z; acc[3] += xv * g0.w;
    acc[4] += xv * g1.x; acc[5] += xv * g1.y;
    acc[6] += xv * g1.z; acc[7] += xv * g1.w;
  }
#pragma unroll
  for (int off = 32; off > 0; off >>= 1) {
#pragma unroll
    for (int e = 0; e < 8; ++e) acc[e] += __shfl_xor(acc[e], off, 64);
  }
  if (lane == 0) {
    float logit[8];
    float m = -1e30f;
#pragma unroll
    for (int e = 0; e < 8; ++e) {
      logit[e] = acc[e] + gb[e];
      m = fmaxf(m, logit[e]);
    }
    float p[8], s = 0.f;
#pragma unroll
    for (int e = 0; e < 8; ++e) { p[e] = expf(logit[e] - m); s += p[e]; }
    float wv[8], wsum = 0.f;
#pragma unroll
    for (int e = 0; e < 8; ++e) {
      float pr = p[e] / s;
      wv[e] = (pr >= 0.1f) ? pr : 0.f;
      wsum += wv[e];
    }
    float invw = (wsum == 0.f) ? 1.f : (1.f / wsum);
#pragma unroll
    for (int e = 0; e < 8; ++e) wout[(size_t)t * 8 + e] = wv[e] * invw;
  }
}

// ---------------------------------------------------------------------------
// Kernel 2: expert_w fp32 [e][k][d] -> bf16 B'[e][d][k] (transposed per expert)
// 32x32 tiles via LDS. Enables contiguous-k B-frag loads + global_load_lds.
// ---------------------------------------------------------------------------
__global__ __launch_bounds__(256) void wtrans_kernel(
    const float* __restrict__ ew, unsigned short* __restrict__ bt) {
  __shared__ float tile[32][33];
  int e  = blockIdx.z;
  int k0 = blockIdx.y * 32;
  int d0 = blockIdx.x * 32;
  int c4 = threadIdx.x & 7;   // float4 within row
  int r  = threadIdx.x >> 3;  // 0..31

  const float* src = ew + ((size_t)e << 20) + (size_t)(k0 + r) * DDIM + d0 + c4 * 4;
  float4 v = *(const float4*)src;
  tile[r][c4 * 4 + 0] = v.x;
  tile[r][c4 * 4 + 1] = v.y;
  tile[r][c4 * 4 + 2] = v.z;
  tile[r][c4 * 4 + 3] = v.w;
  __syncthreads();

  // write B'[e][d0+r][k0 + c4*4 .. +3]
  uint2 pk;
  pk.x = pack_bf16x2(tile[c4 * 4 + 0][r], tile[c4 * 4 + 1][r]);
  pk.y = pack_bf16x2(tile[c4 * 4 + 2][r], tile[c4 * 4 + 3][r]);
  unsigned short* dst = bt + ((size_t)e << 20) + (size_t)(d0 + r) * DDIM + k0 + c4 * 4;
  *(uint2*)dst = pk;
}

// ---------------------------------------------------------------------------
// Kernel 3: fused MoE GEMM. C[t][d] = sum_{e,k} (w[t,e]*x[t,k]) * B'[e][d][k]
//   + sum_e w[t,e]*expert_b[e][d]   (bias folded into epilogue)
// 128x128 tile, BK=32, 4 waves of 4x4 16x16x32 bf16 MFMA.
// ---------------------------------------------------------------------------
__global__ __launch_bounds__(256) void moe_gemm(
    const float* __restrict__ x, const float* __restrict__ w,
    const unsigned short* __restrict__ bw, const float* __restrict__ eb,
    float* __restrict__ out) {
  __shared__ unsigned short As[BM * ALD];  // 10240 B, padded rows
  __shared__ unsigned short Bs[BN * BK];   // 8192 B, [n][k], DMA-contiguous

  int tid  = threadIdx.x;
  int wave = tid >> 6;
  int lane = tid & 63;
  int bm0  = blockIdx.x * BM;   // token tile
  int bn0  = blockIdx.y * BN;   // d tile
  int wm   = (wave >> 1) * 64;
  int wn   = (wave & 1) * 64;

  // A staging mapping: 8 threads per row (float4 each), 4 row-passes
  int aj  = tid & 7;   // float4 index within the 32-wide k slice
  int ar0 = tid >> 3;  // base row 0..31

  floatx4 acc[4][4];
#pragma unroll
  for (int mi = 0; mi < 4; ++mi)
#pragma unroll
    for (int ni = 0; ni < 4; ++ni) acc[mi][ni] = (floatx4)0.f;

  float wrow[4];  // gate weight for this thread's 4 staged rows (per expert)

  for (int kb = 0; kb < KTOT; kb += BK) {
    int e  = kb >> 10;
    int kk = kb & 1023;
    if (kk == 0) {  // expert changed (wave-uniform branch)
#pragma unroll
      for (int it = 0; it < 4; ++it)
        wrow[it] = w[(size_t)(bm0 + ar0 + 32 * it) * 8 + e];
    }

    __syncthreads();  // previous iteration's frag reads complete

    // ---- B tile: async DMA, 8x 1KB wave-chunks (2 per wave) ----
    const unsigned short* bsrc = bw + ((size_t)e << 20) + kk;
#pragma unroll
    for (int c = 0; c < 2; ++c) {
      int chunk = wave * 2 + c;
      const unsigned short* gp =
          bsrc + (size_t)(bn0 + chunk * 16 + (lane >> 2)) * DDIM + (lane & 3) * 8;
      unsigned short* lp = Bs + chunk * 512;  // wave-uniform base
      __builtin_amdgcn_global_load_lds(
          (const __attribute__((address_space(1))) unsigned int*)gp,
          (__attribute__((address_space(3))) unsigned int*)lp, 16, 0, 0);
    }

    // ---- A tile: fp32 load, gate-scale, bf16 pack, LDS store ----
    const float* asrc = x + kk + aj * 4;
#pragma unroll
    for (int it = 0; it < 4; ++it) {
      int r = ar0 + 32 * it;
      float4 v = *(const float4*)(asrc + (size_t)(bm0 + r) * DDIM);
      float s = wrow[it];
      uint2 pk;
      pk.x = pack_bf16x2(v.x * s, v.y * s);
      pk.y = pack_bf16x2(v.z * s, v.w * s);
      *(uint2*)&As[r * ALD + aj * 4] = pk;
    }

    __syncthreads();  // staged data visible

    // ---- fragments + MFMA ----
    int kb8 = (lane >> 4) * 8;
    int fr  = lane & 15;
    short8 af[4], bf[4];
#pragma unroll
    for (int mi = 0; mi < 4; ++mi)
      af[mi] = *(const short8*)&As[(wm + mi * 16 + fr) * ALD + kb8];
#pragma unroll
    for (int ni = 0; ni < 4; ++ni)
      bf[ni] = *(const short8*)&Bs[(wn + ni * 16 + fr) * BK + kb8];
#pragma unroll
    for (int mi = 0; mi < 4; ++mi)
#pragma unroll
      for (int ni = 0; ni < 4; ++ni)
        acc[mi][ni] = __builtin_amdgcn_mfma_f32_16x16x32_bf16(
            af[mi], bf[ni], acc[mi][ni], 0, 0, 0);
  }

  // ---- epilogue: C layout col=lane&15, row=(lane>>4)*4+reg; add weighted bias
  int fr  = lane & 15;
  int cr0 = (lane >> 4) * 4;

  float ebv[8][4];  // expert_b for this thread's 4 columns x 8 experts
#pragma unroll
  for (int e = 0; e < 8; ++e)
#pragma unroll
    for (int ni = 0; ni < 4; ++ni)
      ebv[e][ni] = eb[(size_t)e * DDIM + bn0 + wn + ni * 16 + fr];

#pragma unroll
  for (int mi = 0; mi < 4; ++mi) {
#pragma unroll
    for (int r = 0; r < 4; ++r) {
      int t = bm0 + wm + mi * 16 + cr0 + r;
      const float4* wp = (const float4*)(w + (size_t)t * 8);
      float4 w0 = wp[0];
      float4 w1 = wp[1];
      float* orow = out + (size_t)t * DDIM + bn0 + wn + fr;
#pragma unroll
      for (int ni = 0; ni < 4; ++ni) {
        float bias = w0.x * ebv[0][ni] + w0.y * ebv[1][ni] +
                     w0.z * ebv[2][ni] + w0.w * ebv[3][ni] +
                     w1.x * ebv[4][ni] + w1.y * ebv[5][ni] +
                     w1.z * ebv[6][ni] + w1.w * ebv[7][ni];
        orow[ni * 16] = acc[mi][ni][r] + bias;
      }
    }
  }
}

// ---------------------------------------------------------------------------
extern "C" void kernel_launch(void* const* d_in, const int* in_sizes, int n_in,
                              void* d_out, int out_size, void* d_ws, size_t ws_size,
                              hipStream_t stream) {
  const float* x  = (const float*)d_in[0];   // [4,4096,1024]
  const float* gw = (const float*)d_in[1];   // [1024,8]
  const float* gb = (const float*)d_in[2];   // [8]
  const float* ew = (const float*)d_in[3];   // [8,1024,1024]
  const float* eb = (const float*)d_in[4];   // [8,1024]
  float* out = (float*)d_out;

  // workspace layout: w[16384*8] fp32 (512 KB) | B' bf16 [8*1024*1024] (16 MB)
  float* wbuf = (float*)d_ws;
  unsigned short* bt = (unsigned short*)((char*)d_ws + (size_t)TOK * 8 * 4);

  gate_kernel<<<TOK / 4, 256, 0, stream>>>(x, gw, gb, wbuf);
  wtrans_kernel<<<dim3(DDIM / 32, DDIM / 32, NEXP), 256, 0, stream>>>(ew, bt);
  moe_gemm<<<dim3(TOK / BM, DDIM / BN), 256, 0, stream>>>(x, wbuf, bt, eb, out);
}